// Round 1
// baseline (657.169 us; speedup 1.0000x reference)
//
#include <hip/hip_runtime.h>

typedef __attribute__((ext_vector_type(8))) short s16x8;
typedef __attribute__((ext_vector_type(4))) float f32x4;
typedef unsigned short u16;
typedef unsigned int u32;

__device__ __forceinline__ u16 f2b(float f) {
    u32 u = __float_as_uint(f);
    u32 r = (u + 0x7fffu + ((u >> 16) & 1u)) >> 16;  // RNE bf16
    return (u16)r;
}

#define MFMA16(a, b, c) __builtin_amdgcn_mfma_f32_16x16x32_bf16(a, b, c, 0, 0, 0)
#define GLDS(gp, lp)                                                              \
    __builtin_amdgcn_global_load_lds((const __attribute__((address_space(1))) void*)(gp), \
                                     (__attribute__((address_space(3))) void*)(lp), 16, 0, 0)

// ---------------- elementwise: f32 -> bf16 ----------------
__global__ void k_f2b(const float* __restrict__ in, u16* __restrict__ out, int n4) {
    int i = blockIdx.x * 256 + threadIdx.x;
    if (i >= n4) return;
    float4 v = ((const float4*)in)[i];
    ushort4 o;
    o.x = f2b(v.x); o.y = f2b(v.y); o.z = f2b(v.z); o.w = f2b(v.w);
    ((ushort4*)out)[i] = o;
}

// ---------------- weight transpose+convert: W[K,N] f32 -> Wt[N,K] bf16 ----------------
__global__ void k_wtrans(const float* __restrict__ W, u16* __restrict__ Wt, int K, int N) {
    __shared__ float t[32][33];
    int bx = blockIdx.x * 32, by = blockIdx.y * 32;
    int tx = threadIdx.x, ty = threadIdx.y;
    for (int i = 0; i < 32; i += 8)
        t[ty + i][tx] = W[(size_t)(by + ty + i) * N + bx + tx];
    __syncthreads();
    for (int i = 0; i < 32; i += 8)
        Wt[(size_t)(bx + ty + i) * K + by + tx] = f2b(t[tx][ty + i]);
}

// ---------------- GEMM: C[M,N] f32 = A[M,K]bf16 @ Bt[N,K]bf16^T  (m97-style 128x128x64) ----------------
__global__ __launch_bounds__(256) void gemm_bt(const u16* __restrict__ A, const u16* __restrict__ Bt,
                                               float* __restrict__ C, int M, int N, int K) {
    __shared__ __align__(16) short lA[128 * 64];
    __shared__ __align__(16) short lB[128 * 64];
    const int tid = threadIdx.x, lane = tid & 63, w = tid >> 6;
    const int l15 = lane & 15, lg = lane >> 4;
    const int bm = blockIdx.y, bn = blockIdx.x;
    const int wr = w >> 1, wc = w & 1;
    const int m0 = bm * 128, n0 = bn * 128;
    f32x4 acc[4][4] = {};

    for (int k0 = 0; k0 < K; k0 += 64) {
        #pragma unroll
        for (int i = 0; i < 4; i++) {
            int chunk = w * 4 + i;  // 16 chunks of 8 rows x 64 cols (1 KB)
            int arow = m0 + chunk * 8 + (lane >> 3);
            GLDS(A + (size_t)arow * K + k0 + (lane & 7) * 8, (short*)lA + chunk * 512);
            int brow = n0 + chunk * 8 + (lane >> 3);
            GLDS(Bt + (size_t)brow * K + k0 + (lane & 7) * 8, (short*)lB + chunk * 512);
        }
        __syncthreads();
        #pragma unroll
        for (int ks = 0; ks < 2; ks++) {
            s16x8 af[4], bfr[4];
            #pragma unroll
            for (int m = 0; m < 4; m++)
                af[m] = *(const s16x8*)&lA[(wr * 64 + m * 16 + l15) * 64 + ks * 32 + lg * 8];
            #pragma unroll
            for (int n = 0; n < 4; n++)
                bfr[n] = *(const s16x8*)&lB[(wc * 64 + n * 16 + l15) * 64 + ks * 32 + lg * 8];
            #pragma unroll
            for (int m = 0; m < 4; m++)
                #pragma unroll
                for (int n = 0; n < 4; n++)
                    acc[m][n] = MFMA16(af[m], bfr[n], acc[m][n]);
        }
        __syncthreads();
    }
    const int rbase = m0 + wr * 64, cbase = n0 + wc * 64;
    #pragma unroll
    for (int m = 0; m < 4; m++)
        #pragma unroll
        for (int n = 0; n < 4; n++) {
            int col = cbase + n * 16 + l15;
            int row0 = rbase + m * 16 + lg * 4;
            #pragma unroll
            for (int r = 0; r < 4; r++)
                C[(size_t)(row0 + r) * N + col] = acc[m][n][r];
        }
}

// ---------------- QKV epilogue: Qf f32 + bias + rel -> (Q+rel0)bf16, (Q+rel1)bf16 ----------------
__global__ void k_epi_qk(const float* __restrict__ Qf, const float* __restrict__ bias,
                         const float* __restrict__ rel, u16* __restrict__ Pa, u16* __restrict__ Pc, int n4) {
    int i = blockIdx.x * 256 + threadIdx.x;
    if (i >= n4) return;
    float4 v = ((const float4*)Qf)[i];
    int c = (i * 4) & 1023;
    int d = (i * 4) & 63;
    float4 b = *(const float4*)(bias + c);
    float4 r0 = *(const float4*)(rel + d);
    float4 r1 = *(const float4*)(rel + 64 + d);
    ushort4 oa, oc;
    oa.x = f2b(v.x + b.x + r0.x); oa.y = f2b(v.y + b.y + r0.y);
    oa.z = f2b(v.z + b.z + r0.z); oa.w = f2b(v.w + b.w + r0.w);
    oc.x = f2b(v.x + b.x + r1.x); oc.y = f2b(v.y + b.y + r1.y);
    oc.z = f2b(v.z + b.z + r1.z); oc.w = f2b(v.w + b.w + r1.w);
    ((ushort4*)Pa)[i] = oa;
    ((ushort4*)Pc)[i] = oc;
}

// ---------------- V transpose per group: Vf[g][l][d] f32 (+bv) -> Vt[g][d][l] bf16 ----------------
__global__ void k_vtrans(const float* __restrict__ Vf, const float* __restrict__ bv, u16* __restrict__ Vt) {
    __shared__ float t[64][65];
    const int g = blockIdx.y, lt = blockIdx.x;
    const int tx = threadIdx.x & 63, ty = threadIdx.x >> 6;  // 64 x 4
    const size_t gQ = (size_t)g * 65536;
    for (int i = 0; i < 64; i += 4) {
        int l = lt * 64 + ty + i;
        t[ty + i][tx] = Vf[gQ + (size_t)l * 64 + tx] + bv[((l & 15) * 64 + tx)];
    }
    __syncthreads();
    for (int i = 0; i < 64; i += 4) {
        int d = ty + i;
        Vt[gQ + (size_t)d * 1024 + lt * 64 + tx] = f2b(t[tx][d]);
    }
}

// ---------------- fused dual-map attention ----------------
// grid (16 qtiles, 64 groups), 4 waves/block, wave w owns q rows qt*64+w*16 .. +15
__global__ __launch_bounds__(256) void k_attn(const u16* __restrict__ Qa, const u16* __restrict__ Qc,
                                              const u16* __restrict__ Ka, const u16* __restrict__ Kc,
                                              const u16* __restrict__ Vt,
                                              const float* __restrict__ adjm, const float* __restrict__ comm,
                                              u16* __restrict__ ctx) {
    const int g = blockIdx.y, qt = blockIdx.x;
    const int tid = threadIdx.x, lane = tid & 63, w = tid >> 6;
    const int l15 = lane & 15, lg = lane >> 4;
    __shared__ __align__(16) short lP[4][2][1024];  // [wave][map][16 rows x 64 cols] bf16

    const int q0 = qt * 64 + w * 16;
    const size_t gQ = (size_t)g * 65536;
    const size_t mbase = (size_t)g * 1048576;
    const float scale = 0.125f;

    s16x8 qa[2], qc[2];
    #pragma unroll
    for (int ks = 0; ks < 2; ks++) {
        size_t off = gQ + (size_t)(q0 + l15) * 64 + ks * 32 + lg * 8;
        qa[ks] = *(const s16x8*)(Qa + off);
        qc[ks] = *(const s16x8*)(Qc + off);
    }
    f32x4 ca[4] = {}, cc[4] = {};
    float la[4] = {0.f, 0.f, 0.f, 0.f}, lc[4] = {0.f, 0.f, 0.f, 0.f};

    #pragma unroll 1
    for (int kb = 0; kb < 1024; kb += 64) {
        f32x4 sa[4] = {}, sc[4] = {};
        #pragma unroll
        for (int ks = 0; ks < 2; ks++)
            #pragma unroll
            for (int n = 0; n < 4; n++) {
                size_t koff = gQ + (size_t)(kb + n * 16 + l15) * 64 + ks * 32 + lg * 8;
                s16x8 kfa = *(const s16x8*)(Ka + koff);
                s16x8 kfc = *(const s16x8*)(Kc + koff);
                sa[n] = MFMA16(qa[ks], kfa, sa[n]);
                sc[n] = MFMA16(qc[ks], kfc, sc[n]);
            }
        float suma[4] = {0.f, 0.f, 0.f, 0.f}, sumc[4] = {0.f, 0.f, 0.f, 0.f};
        #pragma unroll
        for (int n = 0; n < 4; n++) {
            int col = kb + n * 16 + l15;
            #pragma unroll
            for (int r = 0; r < 4; r++) {
                int row = q0 + lg * 4 + r;
                float ea = __expf(sa[n][r] * scale);
                float ec = __expf(sc[n][r] * scale);
                suma[r] += ea;
                sumc[r] += ec;
                size_t mi = mbase + (size_t)row * 1024 + col;
                float pa = ea * adjm[mi];
                float pc = ec * comm[mi];
                int lidx = (lg * 4 + r) * 64 + n * 16 + l15;
                lP[w][0][lidx] = (short)f2b(pa);
                lP[w][1][lidx] = (short)f2b(pc);
            }
        }
        #pragma unroll
        for (int r = 0; r < 4; r++) {
            float sA = suma[r], sC = sumc[r];
            #pragma unroll
            for (int m = 8; m >= 1; m >>= 1) {
                sA += __shfl_xor(sA, m);
                sC += __shfl_xor(sC, m);
            }
            la[r] += sA;
            lc[r] += sC;
        }
        // PV: ctx[q][d] += P[q][k] * V[k][d], Bt = Vt[g][d][k]
        #pragma unroll
        for (int ks = 0; ks < 2; ks++) {
            s16x8 pfa = *(const s16x8*)&lP[w][0][l15 * 64 + ks * 32 + lg * 8];
            s16x8 pfc = *(const s16x8*)&lP[w][1][l15 * 64 + ks * 32 + lg * 8];
            #pragma unroll
            for (int d = 0; d < 4; d++) {
                size_t voff = gQ + (size_t)(d * 16 + l15) * 1024 + kb + ks * 32 + lg * 8;
                s16x8 vf = *(const s16x8*)(Vt + voff);
                ca[d] = MFMA16(pfa, vf, ca[d]);
                cc[d] = MFMA16(pfc, vf, cc[d]);
            }
        }
    }
    #pragma unroll
    for (int r = 0; r < 4; r++) {
        float ila = 1.f / la[r], ilc = 1.f / lc[r];
        int row = q0 + lg * 4 + r;
        #pragma unroll
        for (int d = 0; d < 4; d++) {
            float v = ca[d][r] * ila + cc[d][r] * ilc;
            ctx[gQ + (size_t)row * 64 + d * 16 + l15] = f2b(v);
        }
    }
}

// ---------------- bias + relu + bf16 convert ----------------
__global__ void k_relu_b(const float* __restrict__ in, const float* __restrict__ bias,
                         u16* __restrict__ out, int n4, int ncm1) {
    int i = blockIdx.x * 256 + threadIdx.x;
    if (i >= n4) return;
    float4 v = ((const float4*)in)[i];
    int c = (i * 4) & ncm1;
    float4 b = *(const float4*)(bias + c);
    ushort4 o;
    o.x = f2b(fmaxf(v.x + b.x, 0.f));
    o.y = f2b(fmaxf(v.y + b.y, 0.f));
    o.z = f2b(fmaxf(v.z + b.z, 0.f));
    o.w = f2b(fmaxf(v.w + b.w, 0.f));
    ((ushort4*)out)[i] = o;
}

// ---------------- row LayerNorm: t = a[row]+bias+resid[row]; out = LN(t)*g+b (D=1024) ----------------
__global__ __launch_bounds__(256) void k_ln(const float* __restrict__ a, const float* __restrict__ bias,
                                            const float* __restrict__ resid, const float* __restrict__ gamma,
                                            const float* __restrict__ beta, float* __restrict__ out,
                                            u16* __restrict__ outb) {
    const int row = blockIdx.x, tid = threadIdx.x;
    const size_t base = (size_t)row * 1024 + tid * 4;
    float4 av = *(const float4*)(a + base);
    float4 rv = *(const float4*)(resid + base);
    float4 bv = *(const float4*)(bias + tid * 4);
    float t0 = av.x + rv.x + bv.x, t1 = av.y + rv.y + bv.y;
    float t2 = av.z + rv.z + bv.z, t3 = av.w + rv.w + bv.w;
    __shared__ float red[4];
    float s = t0 + t1 + t2 + t3;
    #pragma unroll
    for (int m = 32; m >= 1; m >>= 1) s += __shfl_xor(s, m);
    int w = tid >> 6;
    if ((tid & 63) == 0) red[w] = s;
    __syncthreads();
    float mean = (red[0] + red[1] + red[2] + red[3]) * (1.f / 1024.f);
    float d0 = t0 - mean, d1 = t1 - mean, d2 = t2 - mean, d3 = t3 - mean;
    float q = d0 * d0 + d1 * d1 + d2 * d2 + d3 * d3;
    __syncthreads();
    #pragma unroll
    for (int m = 32; m >= 1; m >>= 1) q += __shfl_xor(q, m);
    if ((tid & 63) == 0) red[w] = q;
    __syncthreads();
    float var = (red[0] + red[1] + red[2] + red[3]) * (1.f / 1024.f);
    float rs = rsqrtf(var + 1e-5f);
    float4 gv = *(const float4*)(gamma + tid * 4);
    float4 bev = *(const float4*)(beta + tid * 4);
    float o0 = d0 * rs * gv.x + bev.x, o1 = d1 * rs * gv.y + bev.y;
    float o2 = d2 * rs * gv.z + bev.z, o3 = d3 * rs * gv.w + bev.w;
    *(float4*)(out + base) = make_float4(o0, o1, o2, o3);
    if (outb) {
        ushort4 ob;
        ob.x = f2b(o0); ob.y = f2b(o1); ob.z = f2b(o2); ob.w = f2b(o3);
        *(ushort4*)(outb + base) = ob;
    }
}

extern "C" void kernel_launch(void* const* d_in, const int* in_sizes, int n_in,
                              void* d_out, int out_size, void* d_ws, size_t ws_size,
                              hipStream_t stream) {
    const float* x    = (const float*)d_in[0];
    const float* adjm = (const float*)d_in[1];
    const float* comm = (const float*)d_in[2];
    const float* rel  = (const float*)d_in[3];
    const float* Wq   = (const float*)d_in[4];
    const float* bq   = (const float*)d_in[5];
    const float* Wk   = (const float*)d_in[6];
    const float* bk   = (const float*)d_in[7];
    const float* Wv   = (const float*)d_in[8];
    const float* bv   = (const float*)d_in[9];
    const float* Wo   = (const float*)d_in[10];
    const float* bo   = (const float*)d_in[11];
    const float* g1   = (const float*)d_in[12];
    const float* be1  = (const float*)d_in[13];
    const float* W1   = (const float*)d_in[14];
    const float* b1   = (const float*)d_in[15];
    const float* W2   = (const float*)d_in[16];
    const float* b2   = (const float*)d_in[17];
    const float* g2   = (const float*)d_in[18];
    const float* be2  = (const float*)d_in[19];
    float* out = (float*)d_out;

    char* ws = (char*)d_ws;
    const size_t MB = 1048576;
    // liveness-packed layout, peak 176 MiB
    u16*   xb    = (u16*)(ws + 0 * MB);      // 8 MiB  (dead after QKV gemms)
    u16*   Wqt   = (u16*)(ws + 8 * MB);      // 2 MiB
    u16*   Wkt   = (u16*)(ws + 10 * MB);
    u16*   Wvt   = (u16*)(ws + 12 * MB);
    u16*   Wot   = (u16*)(ws + 14 * MB);
    u16*   W1t   = (u16*)(ws + 16 * MB);     // 8 MiB
    u16*   W2t   = (u16*)(ws + 24 * MB);     // 8 MiB
    float* Qf    = (float*)(ws + 32 * MB);   // 16 MiB (dead after epi)
    float* Kf    = (float*)(ws + 48 * MB);   // 16 MiB
    float* Vf    = (float*)(ws + 64 * MB);   // 16 MiB
    u16*   Qab   = (u16*)(ws + 80 * MB);     // 8 MiB  (dead after attn)
    u16*   Qcb   = (u16*)(ws + 88 * MB);
    u16*   Kab   = (u16*)(ws + 96 * MB);
    u16*   Kcb   = (u16*)(ws + 104 * MB);
    u16*   Vtb   = (u16*)(ws + 112 * MB);    // 8 MiB
    u16*   ctx   = (u16*)(ws + 120 * MB);    // 8 MiB  (dead after Wo gemm)
    float* ctxWo = (float*)(ws + 32 * MB);   // reuse Qf
    float* out1  = (float*)(ws + 48 * MB);   // reuse Kf (live to LN2)
    u16*   out1b = (u16*)(ws + 64 * MB);     // reuse Vf
    float* ff1   = (float*)(ws + 80 * MB);   // 64 MiB, reuse attn region
    u16*   rb    = (u16*)(ws + 144 * MB);    // 32 MiB [144,176)
    float* ff2   = (float*)(ws + 0 * MB);    // 16 MiB, reuse xb+W region

    dim3 tb(32, 8);
    // 1. casts / weight prep
    k_f2b<<<4096, 256, 0, stream>>>(x, xb, 1048576);
    k_wtrans<<<dim3(32, 32), tb, 0, stream>>>(Wq, Wqt, 1024, 1024);
    k_wtrans<<<dim3(32, 32), tb, 0, stream>>>(Wk, Wkt, 1024, 1024);
    k_wtrans<<<dim3(32, 32), tb, 0, stream>>>(Wv, Wvt, 1024, 1024);
    k_wtrans<<<dim3(32, 32), tb, 0, stream>>>(Wo, Wot, 1024, 1024);
    k_wtrans<<<dim3(128, 32), tb, 0, stream>>>(W1, W1t, 1024, 4096);  // W1[1024,4096] -> W1t[4096,1024]
    k_wtrans<<<dim3(32, 128), tb, 0, stream>>>(W2, W2t, 4096, 1024);  // W2[4096,1024] -> W2t[1024,4096]
    // 2. QKV projections
    gemm_bt<<<dim3(8, 32), 256, 0, stream>>>(xb, Wqt, Qf, 4096, 1024, 1024);
    gemm_bt<<<dim3(8, 32), 256, 0, stream>>>(xb, Wkt, Kf, 4096, 1024, 1024);
    gemm_bt<<<dim3(8, 32), 256, 0, stream>>>(xb, Wvt, Vf, 4096, 1024, 1024);
    // 3. epilogues: +bias, +rel variants, V transpose
    k_epi_qk<<<4096, 256, 0, stream>>>(Qf, bq, rel, Qab, Qcb, 1048576);
    k_epi_qk<<<4096, 256, 0, stream>>>(Kf, bk, rel, Kab, Kcb, 1048576);
    k_vtrans<<<dim3(16, 64), 256, 0, stream>>>(Vf, bv, Vtb);
    // 4. dual-map attention
    k_attn<<<dim3(16, 64), 256, 0, stream>>>(Qab, Qcb, Kab, Kcb, Vtb, adjm, comm, ctx);
    // 5. output projection + LN1 (adds bo + residual x)
    gemm_bt<<<dim3(8, 32), 256, 0, stream>>>(ctx, Wot, ctxWo, 4096, 1024, 1024);
    k_ln<<<4096, 256, 0, stream>>>(ctxWo, bo, x, g1, be1, out1, out1b);
    // 6. FFN
    gemm_bt<<<dim3(32, 32), 256, 0, stream>>>(out1b, W1t, ff1, 4096, 4096, 1024);
    k_relu_b<<<16384, 256, 0, stream>>>(ff1, b1, rb, 4194304, 4095);
    gemm_bt<<<dim3(8, 32), 256, 0, stream>>>(rb, W2t, ff2, 4096, 1024, 4096);
    // 7. LN2 (adds b2 + residual out1) -> final output
    k_ln<<<4096, 256, 0, stream>>>(ff2, b2, out1, g2, be2, out, nullptr);
}